// Round 12
// baseline (89.750 us; speedup 1.0000x reference)
//
#include <hip/hip_runtime.h>
#include <hip/hip_bf16.h>
#include <math.h>

constexpr int NP  = 6144;   // rows
constexpr int DM  = 256;    // d_model
constexpr int DFF = 1024;   // ff dim
constexpr float LNEPS = 1e-5f;

typedef __attribute__((ext_vector_type(8))) short short8;
typedef __attribute__((ext_vector_type(4))) short short4v;
typedef __attribute__((ext_vector_type(4))) float f32x4;

__device__ __forceinline__ short f2bf(float f) {
    unsigned u = __builtin_bit_cast(unsigned, f);
    unsigned r = u + 0x7FFFu + ((u >> 16) & 1u);   // RNE
    return (short)(r >> 16);
}
__device__ __forceinline__ float bf2f(short s) {
    unsigned u = ((unsigned)(unsigned short)s) << 16;
    return __builtin_bit_cast(float, u);
}

// global->LDS direct 16B copy. LDS dest = wave-uniform base + lane*16;
// per-lane global src carries the swizzle (guide rule #21).
#define GLOAD16(gp, lp)                                                        \
    __builtin_amdgcn_global_load_lds(                                          \
        (const __attribute__((address_space(1))) unsigned int*)(gp),           \
        (__attribute__((address_space(3))) unsigned int*)(lp), 16, 0, 0)

// LDS tile: linear [rows][64] shorts; chunk c of row r at slot c^(r&7).
__device__ __forceinline__ int lds_idx(int row, int chunk) {
    return row * 64 + ((chunk ^ (row & 7)) * 8);
}

// ---------------------------------------------------------------------------
// prep: blocks 0..767 transpose+convert weights fp32[K][N] -> bf16[N][K];
// blocks 768..791 segment bounds; blocks 792..1559 convert x -> bf16.
// ---------------------------------------------------------------------------
__global__ __launch_bounds__(256) void prep_kernel(
    const float* __restrict__ qkv_w, const float* __restrict__ out_w,
    const float* __restrict__ ff_w1, const float* __restrict__ ff_w2,
    short* __restrict__ qkvT, short* __restrict__ outT,
    short* __restrict__ ff1T, short* __restrict__ ff2T,
    const int* __restrict__ dom, int* __restrict__ seg_s,
    int* __restrict__ seg_e, const float* __restrict__ x,
    short* __restrict__ xB) {
    int b = blockIdx.x;
    if (b >= 792) {   // x -> bf16
        int i = (b - 792) * 2048 + threadIdx.x * 8;
        float4 a0 = *(const float4*)&x[i];
        float4 a1 = *(const float4*)&x[i + 4];
        short8 v = { f2bf(a0.x), f2bf(a0.y), f2bf(a0.z), f2bf(a0.w),
                     f2bf(a1.x), f2bf(a1.y), f2bf(a1.z), f2bf(a1.w) };
        *(short8*)&xB[i] = v;
        return;
    }
    if (b >= 768) {   // segment bounds
        int i = (b - 768) * 256 + threadIdx.x;
        if (i >= NP) return;
        int d = dom[i];
        int s = i;
        while (s > 0 && dom[s - 1] == d) --s;
        int e = i + 1;
        while (e < NP && dom[e] == d) ++e;
        seg_s[i] = s;
        seg_e[i] = e;
        return;
    }
    const float* src;
    short* dst;
    int K, Nn;
    if (b < 192)      { src = qkv_w; dst = qkvT; K = 256;  Nn = 768; }
    else if (b < 256) { b -= 192; src = out_w; dst = outT; K = 256;  Nn = 256; }
    else if (b < 512) { b -= 256; src = ff_w1; dst = ff1T; K = 256;  Nn = 1024; }
    else              { b -= 512; src = ff_w2; dst = ff2T; K = 1024; Nn = 256; }
    int tpr = Nn / 32;
    int k0 = (b / tpr) * 32, n0 = (b % tpr) * 32;

    __shared__ float lds[32][36];
    int t = threadIdx.x;
    {
        int k = t >> 3, n = (t & 7) * 4;
        *(float4*)&lds[k][n] = *(const float4*)&src[(size_t)(k0 + k) * Nn + n0 + n];
    }
    __syncthreads();
    {
        int n = t >> 3, ks = (t & 7) * 4;
        short4v o = { f2bf(lds[ks + 0][n]), f2bf(lds[ks + 1][n]),
                      f2bf(lds[ks + 2][n]), f2bf(lds[ks + 3][n]) };
        *(short4v*)&dst[(size_t)(n0 + n) * K + k0 + ks] = o;
    }
}

// ---------------------------------------------------------------------------
// mgemm128: C_bf16[M,Nn] = A_bf16[M,K] @ Bt_bf16[Nn,K]^T + bias.
// Tile 128x128, BK=64, 4 waves (2x2), wave owns 64x64 = 4x4 frags.
// ---------------------------------------------------------------------------
__global__ __launch_bounds__(256) void mgemm128(
    const short* __restrict__ A, const short* __restrict__ Bt,
    const float* __restrict__ bias, short* __restrict__ C, int Nn, int K) {
    __shared__ __align__(16) short As[128 * 64];
    __shared__ __align__(16) short Bs[128 * 64];

    const int tid = threadIdx.x, lane = tid & 63, w = tid >> 6;
    const int wm = (w >> 1) * 64, wn = (w & 1) * 64;
    const int rowBase = blockIdx.y * 128, colBase = blockIdx.x * 128;
    const int lr = lane >> 3, sc = (lane & 7) ^ lr;
    const int fr = lane & 15, g4 = lane >> 4;

    f32x4 acc[4][4];
#pragma unroll
    for (int i = 0; i < 4; ++i)
#pragma unroll
        for (int j = 0; j < 4; ++j) acc[i][j] = f32x4{0.f, 0.f, 0.f, 0.f};

    for (int k0 = 0; k0 < K; k0 += 64) {
#pragma unroll
        for (int i = 0; i < 4; ++i) {
            int g = w * 4 + i;
            int row = g * 8 + lr;
            GLOAD16(A  + (size_t)(rowBase + row) * K + k0 + sc * 8, &As[g * 512]);
            GLOAD16(Bt + (size_t)(colBase + row) * K + k0 + sc * 8, &Bs[g * 512]);
        }
        __syncthreads();

#pragma unroll
        for (int kk = 0; kk < 2; ++kk) {
            int j = kk * 4 + g4;
            short8 af[4], bfv[4];
#pragma unroll
            for (int f = 0; f < 4; ++f) {
                af[f]  = *(const short8*)&As[lds_idx(wm + f * 16 + fr, j)];
                bfv[f] = *(const short8*)&Bs[lds_idx(wn + f * 16 + fr, j)];
            }
#pragma unroll
            for (int fm = 0; fm < 4; ++fm)
#pragma unroll
                for (int fn = 0; fn < 4; ++fn)
                    acc[fm][fn] = __builtin_amdgcn_mfma_f32_16x16x32_bf16(
                        af[fm], bfv[fn], acc[fm][fn], 0, 0, 0);
        }
        __syncthreads();
    }

    const int cr = g4 * 4;
#pragma unroll
    for (int fm = 0; fm < 4; ++fm)
#pragma unroll
        for (int fn = 0; fn < 4; ++fn) {
            int c = colBase + wn + fn * 16 + fr;
            float bv = bias[c];
#pragma unroll
            for (int j = 0; j < 4; ++j) {
                int r = rowBase + wm + fm * 16 + cr + j;
                C[(size_t)r * Nn + c] = f2bf(acc[fm][fn][j] + bv);
            }
        }
}

// ---------------------------------------------------------------------------
// attnln: fused {segment attention for 32 rows} + {out-proj GEMM} +
// {residual + LN1} -> x1 bf16. 192 blocks x 512 threads. (R6 structure.)
// ---------------------------------------------------------------------------
__global__ __launch_bounds__(512) void attnln_kernel(
    const short* __restrict__ qkvB, const int* __restrict__ seg_s,
    const int* __restrict__ seg_e, const short* __restrict__ outT,
    const float* __restrict__ out_b, const float* __restrict__ xres,
    const float* __restrict__ gw, const float* __restrict__ bw,
    short* __restrict__ x1) {
    __shared__ __align__(16) short As[32 * 256];   // attn out, swizzled
    __shared__ __align__(16) short Bs[256 * 64];
    __shared__ float r1[8][32], r2[8][32];

    const int tid = threadIdx.x, lane = tid & 63, w = tid >> 6;
    const int rowBase = blockIdx.x * 32;
    const int lr = lane >> 3, sc = (lane & 7) ^ lr;
    const int fr = lane & 15, g4 = lane >> 4;

    // ---- attention (32 rows x 4 heads = 128 tasks, 8-lane groups) ----
    {
        const int l8 = lane & 7;
        const int G  = (w << 3) | (lane >> 3);
#pragma unroll
        for (int s = 0; s < 2; ++s) {
            int task = G + s * 64;
            int r = task >> 2, h = task & 3;
            int row = rowBase + r;
            short8 qv = *(const short8*)&qkvB[(size_t)row * 768 + h * 64 + l8 * 8];
            float qd[8];
#pragma unroll
            for (int e = 0; e < 8; ++e) qd[e] = bf2f(qv[e]);
            int ss = seg_s[row], ee = seg_e[row];
            float m = -INFINITY, l = 0.0f;
            float acc[8] = {0.f, 0.f, 0.f, 0.f, 0.f, 0.f, 0.f, 0.f};
            for (int j = ss; j < ee; ++j) {
                short8 kv = *(const short8*)&qkvB[(size_t)j * 768 + 256 + h * 64 + l8 * 8];
                short8 vv = *(const short8*)&qkvB[(size_t)j * 768 + 512 + h * 64 + l8 * 8];
                float prod = 0.f;
#pragma unroll
                for (int e = 0; e < 8; ++e) prod += qd[e] * bf2f(kv[e]);
                prod += __shfl_xor(prod, 1);
                prod += __shfl_xor(prod, 2);
                prod += __shfl_xor(prod, 4);
                float score = prod * 0.125f;
                float mn = fmaxf(m, score);
                float scale = __expf(m - mn);
                float p = __expf(score - mn);
                l = l * scale + p;
#pragma unroll
                for (int e = 0; e < 8; ++e) acc[e] = acc[e] * scale + p * bf2f(vv[e]);
                m = mn;
            }
            float inv = 1.0f / l;
            int c = h * 8 + l8;
            short8 o;
#pragma unroll
            for (int e = 0; e < 8; ++e) o[e] = f2bf(acc[e] * inv);
            *(short8*)&As[r * 256 + ((c ^ (r & 7)) * 8)] = o;
        }
    }
    __syncthreads();

    // ---- GEMM (A=attn LDS, B=outT staged) + residual + LN1 ----
    f32x4 acc[2][2];
#pragma unroll
    for (int i = 0; i < 2; ++i)
#pragma unroll
        for (int j = 0; j < 2; ++j) acc[i][j] = f32x4{0.f, 0.f, 0.f, 0.f};

    for (int k0 = 0; k0 < 256; k0 += 64) {
#pragma unroll
        for (int i = 0; i < 4; ++i) {
            int g = w * 4 + i;
            GLOAD16(outT + (size_t)(g * 8 + lr) * 256 + k0 + sc * 8, &Bs[g * 512]);
        }
        __syncthreads();
#pragma unroll
        for (int kk = 0; kk < 2; ++kk) {
            int j = kk * 4 + g4;
            int cj = (k0 >> 3) + j;
            short8 af[2], bfv[2];
            af[0] = *(const short8*)&As[fr * 256 + ((cj ^ (fr & 7)) * 8)];
            af[1] = *(const short8*)&As[(16 + fr) * 256 + ((cj ^ (fr & 7)) * 8)];
#pragma unroll
            for (int fn = 0; fn < 2; ++fn)
                bfv[fn] = *(const short8*)&Bs[lds_idx(w * 32 + fn * 16 + fr, j)];
#pragma unroll
            for (int fm = 0; fm < 2; ++fm)
#pragma unroll
                for (int fn = 0; fn < 2; ++fn)
                    acc[fm][fn] = __builtin_amdgcn_mfma_f32_16x16x32_bf16(
                        af[fm], bfv[fn], acc[fm][fn], 0, 0, 0);
        }
        __syncthreads();
    }

    float v[2][2][4], p1[2][4], p2[2][4];
#pragma unroll
    for (int fm = 0; fm < 2; ++fm)
#pragma unroll
        for (int j = 0; j < 4; ++j) { p1[fm][j] = 0.f; p2[fm][j] = 0.f; }
#pragma unroll
    for (int fm = 0; fm < 2; ++fm)
#pragma unroll
        for (int fn = 0; fn < 2; ++fn) {
            int c = w * 32 + fn * 16 + fr;
            float bv = out_b[c];
#pragma unroll
            for (int j = 0; j < 4; ++j) {
                int r = rowBase + fm * 16 + g4 * 4 + j;
                float t = acc[fm][fn][j] + bv + xres[(size_t)r * 256 + c];
                v[fm][fn][j] = t;
                p1[fm][j] += t;
                p2[fm][j] += t * t;
            }
        }
#pragma unroll
    for (int m = 1; m < 16; m <<= 1)
#pragma unroll
        for (int fm = 0; fm < 2; ++fm)
#pragma unroll
            for (int j = 0; j < 4; ++j) {
                p1[fm][j] += __shfl_xor(p1[fm][j], m);
                p2[fm][j] += __shfl_xor(p2[fm][j], m);
            }
    if (fr == 0) {
#pragma unroll
        for (int fm = 0; fm < 2; ++fm)
#pragma unroll
            for (int j = 0; j < 4; ++j) {
                r1[w][fm * 16 + g4 * 4 + j] = p1[fm][j];
                r2[w][fm * 16 + g4 * 4 + j] = p2[fm][j];
            }
    }
    __syncthreads();
#pragma unroll
    for (int fm = 0; fm < 2; ++fm)
#pragma unroll
        for (int j = 0; j < 4; ++j) {
            int rl = fm * 16 + g4 * 4 + j;
            int r = rowBase + rl;
            float s1 = 0.f, s2 = 0.f;
#pragma unroll
            for (int ww = 0; ww < 8; ++ww) { s1 += r1[ww][rl]; s2 += r2[ww][rl]; }
            float mu = s1 * (1.0f / 256.0f);
            float var = s2 * (1.0f / 256.0f) - mu * mu;
            float rstd = rsqrtf(var + LNEPS);
#pragma unroll
            for (int fn = 0; fn < 2; ++fn) {
                int c = w * 32 + fn * 16 + fr;
                float o = (v[fm][fn][j] - mu) * rstd * gw[c] + bw[c];
                x1[(size_t)r * 256 + c] = f2bf(o);
            }
        }
}

// ---------------------------------------------------------------------------
// ffn: fused h = gelu(x1 @ ff1T^T + b1); out = LN2(x1 + h @ ff2T^T + b2).
// 192 blocks x 512 threads, 32 rows/block.
// KEY CHANGE vs R9/R11: weights go through LDS via global_load_lds (async,
// coalesced), NOT per-lane direct loads (R9/R11: compiler serialized ~64
// dependent L2 loads at VGPR=64 -> 43us latency-bound). Per k-step: stage
// Ws[128x64] (2 gloads/wave) -> sync -> MFMA from swizzled LDS -> sync.
// FFN1 = 2 chunks x 4 hc-tiles x 4 ksteps; gelu -> Hs per tile.
// FFN2 = per chunk 2 out-tiles x 8 ksteps, K accumulated across chunks.
// h never touches HBM. LDS = 16+16+32+2 = 66 KB.
// ---------------------------------------------------------------------------
__global__ __launch_bounds__(512) void ffn_kernel(
    const short* __restrict__ x1, const short* __restrict__ ff1T,
    const float* __restrict__ ff_b1, const short* __restrict__ ff2T,
    const float* __restrict__ ff_b2, const float* __restrict__ gw,
    const float* __restrict__ bw, float* __restrict__ out) {
    __shared__ __align__(16) short As[32 * 256];    // x1 strip, 16 KB
    __shared__ __align__(16) short Ws[128 * 64];    // weight tile, 16 KB
    __shared__ __align__(16) short Hs[32 * 512];    // h half-strip, 32 KB
    __shared__ float red1[8][32], red2[8][32];

    const int tid = threadIdx.x, lane = tid & 63, w = tid >> 6;
    const int fr = lane & 15, g4 = lane >> 4;
    const int lr = lane >> 3, sc = (lane & 7) ^ lr;
    const int r0 = blockIdx.x * 32;

    // stage x1 strip (32x256 bf16) into As, chunk-XOR swizzled.
#pragma unroll
    for (int i = 0; i < 2; ++i) {
        int g = w * 2 + i;
        int row = g * 2 + (lane >> 5);
        int chunk = (lane & 31) ^ (row & 7);
        GLOAD16(x1 + (size_t)(r0 + row) * 256 + chunk * 8, &As[g * 512]);
    }
    __syncthreads();

    f32x4 a2[2][2];
#pragma unroll
    for (int i = 0; i < 2; ++i) { a2[i][0] = f32x4{0,0,0,0}; a2[i][1] = f32x4{0,0,0,0}; }

#pragma unroll
    for (int c = 0; c < 2; ++c) {
        // ---- FFN1: 4 hc-tiles of 128 h-cols each ----
#pragma unroll
        for (int t = 0; t < 4; ++t) {
            f32x4 a1[2];
            a1[0] = f32x4{0,0,0,0};
            a1[1] = f32x4{0,0,0,0};
#pragma unroll
            for (int ks = 0; ks < 4; ++ks) {
#pragma unroll
                for (int i2 = 0; i2 < 2; ++i2) {
                    int g = w * 2 + i2;
                    int row = c * 512 + t * 128 + g * 8 + lr;   // ff1T row (h-col)
                    GLOAD16(ff1T + (size_t)row * 256 + ks * 64 + sc * 8, &Ws[g * 512]);
                }
                __syncthreads();
#pragma unroll
                for (int kk = 0; kk < 2; ++kk) {
                    int j = kk * 4 + g4;
                    int sw = ((ks * 8 + j) ^ (fr & 7)) * 8;
                    short8 bv0 = *(const short8*)&As[fr * 256 + sw];
                    short8 bv1 = *(const short8*)&As[(16 + fr) * 256 + sw];
                    short8 af = *(const short8*)&Ws[lds_idx(w * 16 + fr, j)];
                    a1[0] = __builtin_amdgcn_mfma_f32_16x16x32_bf16(af, bv0, a1[0], 0, 0, 0);
                    a1[1] = __builtin_amdgcn_mfma_f32_16x16x32_bf16(af, bv1, a1[1], 0, 0, 0);
                }
                __syncthreads();
            }
            // bias + gelu -> Hs. h-col (in chunk) = t*128 + w*16 + g4*4 + reg
            int hc = t * 128 + w * 16 + g4 * 4;
            float4 bb = *(const float4*)&ff_b1[c * 512 + hc];
            const float* bbp = (const float*)&bb;
#pragma unroll
            for (int fn = 0; fn < 2; ++fn) {
                int p = fn * 16 + fr;
                short4v o;
#pragma unroll
                for (int reg = 0; reg < 4; ++reg) {
                    float v = a1[fn][reg] + bbp[reg];
                    v = 0.5f * v * (1.0f + erff(v * 0.70710678118654752f));
                    o[reg] = f2bf(v);
                }
                *(short4v*)&Hs[p * 512 + (((hc >> 3) ^ (p & 7)) * 8) + (hc & 7)] = o;
            }
        }

        // ---- FFN2 partial (K-slice c*512..+512): 2 out-tiles of 128 ----
#pragma unroll
        for (int u = 0; u < 2; ++u) {
#pragma unroll
            for (int ks = 0; ks < 8; ++ks) {
#pragma unroll
                for (int i2 = 0; i2 < 2; ++i2) {
                    int g = w * 2 + i2;
                    int row = u * 128 + g * 8 + lr;             // ff2T row (out-col)
                    GLOAD16(ff2T + (size_t)row * 1024 + c * 512 + ks * 64 + sc * 8,
                            &Ws[g * 512]);
                }
                __syncthreads();
#pragma unroll
                for (int kk = 0; kk < 2; ++kk) {
                    int j = kk * 4 + g4;
                    int sw = ((ks * 8 + j) ^ (fr & 7)) * 8;
                    short8 bv0 = *(const short8*)&Hs[fr * 512 + sw];
                    short8 bv1 = *(const short8*)&Hs[(16 + fr) * 512 + sw];
                    short8 af = *(const short8*)&Ws[lds_idx(w * 16 + fr, j)];
                    a2[u][0] = __builtin_amdgcn_mfma_f32_16x16x32_bf16(af, bv0, a2[u][0], 0, 0, 0);
                    a2[u][1] = __builtin_amdgcn_mfma_f32_16x16x32_bf16(af, bv1, a2[u][1], 0, 0, 0);
                }
                __syncthreads();
            }
        }
    }

    // ---- bias + residual(x1 from As) + LN2 -> out (fp32) ----
    // out-col c0 = u*128 + w*16 + g4*4 + reg; pulse p = fn*16 + fr
    float vv[2][2][4];
    float s1[2] = {0.f, 0.f}, s2[2] = {0.f, 0.f};
#pragma unroll
    for (int u = 0; u < 2; ++u) {
        int c0 = u * 128 + w * 16 + g4 * 4;
        float4 bb = *(const float4*)&ff_b2[c0];
        const float* bbp = (const float*)&bb;
#pragma unroll
        for (int fn = 0; fn < 2; ++fn) {
            int p = fn * 16 + fr;
            short4v rx = *(const short4v*)&As[p * 256 + (((c0 >> 3) ^ (p & 7)) * 8) + (c0 & 7)];
#pragma unroll
            for (int reg = 0; reg < 4; ++reg) {
                float t = a2[u][fn][reg] + bbp[reg] + bf2f(rx[reg]);
                vv[u][fn][reg] = t;
                s1[fn] += t;
                s2[fn] += t * t;
            }
        }
    }
#pragma unroll
    for (int fn = 0; fn < 2; ++fn) {
        s1[fn] += __shfl_xor(s1[fn], 16);
        s1[fn] += __shfl_xor(s1[fn], 32);
        s2[fn] += __shfl_xor(s2[fn], 16);
        s2[fn] += __shfl_xor(s2[fn], 32);
    }
    if (g4 == 0) {
#pragma unroll
        for (int fn = 0; fn < 2; ++fn) {
            red1[w][fn * 16 + fr] = s1[fn];
            red2[w][fn * 16 + fr] = s2[fn];
        }
    }
    __syncthreads();
#pragma unroll
    for (int fn = 0; fn < 2; ++fn) {
        int p = fn * 16 + fr;
        float S1 = 0.f, S2 = 0.f;
#pragma unroll
        for (int ww = 0; ww < 8; ++ww) { S1 += red1[ww][p]; S2 += red2[ww][p]; }
        float mu = S1 * (1.0f / 256.0f);
        float var = S2 * (1.0f / 256.0f) - mu * mu;
        float rstd = rsqrtf(var + LNEPS);
#pragma unroll
        for (int u = 0; u < 2; ++u) {
            int c0 = u * 128 + w * 16 + g4 * 4;
            float4 gg = *(const float4*)&gw[c0];
            float4 b4 = *(const float4*)&bw[c0];
            const float* ggp = (const float*)&gg;
            const float* bp  = (const float*)&b4;
            float4 o;
            float* op = (float*)&o;
#pragma unroll
            for (int reg = 0; reg < 4; ++reg)
                op[reg] = (vv[u][fn][reg] - mu) * rstd * ggp[reg] + bp[reg];
            *(float4*)&out[(size_t)(r0 + p) * 256 + c0] = o;
        }
    }
}

// ---------------------------------------------------------------------------
extern "C" void kernel_launch(void* const* d_in, const int* in_sizes, int n_in,
                              void* d_out, int out_size, void* d_ws, size_t ws_size,
                              hipStream_t stream) {
    const float* x      = (const float*)d_in[0];
    const int*   dom    = (const int*)d_in[1];
    const float* qkv_w  = (const float*)d_in[2];
    const float* qkv_b  = (const float*)d_in[3];
    const float* out_w  = (const float*)d_in[4];
    const float* out_b  = (const float*)d_in[5];
    const float* ff_w1  = (const float*)d_in[6];
    const float* ff_b1  = (const float*)d_in[7];
    const float* ff_w2  = (const float*)d_in[8];
    const float* ff_b2  = (const float*)d_in[9];
    const float* ln1_g  = (const float*)d_in[10];
    const float* ln1_b  = (const float*)d_in[11];
    const float* ln2_g  = (const float*)d_in[12];
    const float* ln2_b  = (const float*)d_in[13];
    float* out = (float*)d_out;

    short* xB     = (short*)d_ws;                    // NP x 256
    short* qkvB   = xB + (size_t)NP * 256;           // NP x 768
    short* x1     = qkvB + (size_t)NP * 768;         // NP x 256
    short* qkvT   = x1 + (size_t)NP * 256;           // 768 x 256
    short* outT   = qkvT + 768 * 256;                // 256 x 256
    short* ff1T   = outT + 256 * 256;                // 1024 x 256
    short* ff2T   = ff1T + 1024 * 256;               // 256 x 1024
    int* seg_s    = (int*)(ff2T + 256 * 1024);
    int* seg_e    = seg_s + NP;

    // 0) weight transpose/convert + segment bounds + x->bf16
    prep_kernel<<<1560, 256, 0, stream>>>(qkv_w, out_w, ff_w1, ff_w2,
                                          qkvT, outT, ff1T, ff2T,
                                          dom, seg_s, seg_e, x, xB);

    // 1) qkv = x @ qkv_w + qkv_b                (bf16 out)
    mgemm128<<<dim3(768 / 128, NP / 128), 256, 0, stream>>>(
        xB, qkvT, qkv_b, qkvB, 768, 256);

    // 2) x1 = LN1(x + attn(qkv) @ out_w + out_b)   (fused, bf16 out)
    attnln_kernel<<<NP / 32, 512, 0, stream>>>(
        qkvB, seg_s, seg_e, outT, out_b, x, ln1_g, ln1_b, x1);

    // 3) out = LN2(x1 + gelu(x1@ff_w1+b1) @ ff_w2 + b2)   (fused FFN)
    ffn_kernel<<<NP / 32, 512, 0, stream>>>(
        x1, ff1T, ff_b1, ff2T, ff_b2, ln2_g, ln2_b, out);
}

// Round 13
// 77.691 us; speedup vs baseline: 1.1552x; 1.1552x over previous
//
#include <hip/hip_runtime.h>
#include <hip/hip_bf16.h>
#include <math.h>

constexpr int NP  = 6144;   // rows
constexpr int DM  = 256;    // d_model
constexpr int DFF = 1024;   // ff dim
constexpr float LNEPS = 1e-5f;

typedef __attribute__((ext_vector_type(8))) short short8;
typedef __attribute__((ext_vector_type(4))) short short4v;
typedef __attribute__((ext_vector_type(4))) float f32x4;

__device__ __forceinline__ short f2bf(float f) {
    unsigned u = __builtin_bit_cast(unsigned, f);
    unsigned r = u + 0x7FFFu + ((u >> 16) & 1u);   // RNE
    return (short)(r >> 16);
}
__device__ __forceinline__ float bf2f(short s) {
    unsigned u = ((unsigned)(unsigned short)s) << 16;
    return __builtin_bit_cast(float, u);
}

// global->LDS direct 16B copy. LDS dest = wave-uniform base + lane*16;
// per-lane global src carries the swizzle (guide rule #21).
#define GLOAD16(gp, lp)                                                        \
    __builtin_amdgcn_global_load_lds(                                          \
        (const __attribute__((address_space(1))) unsigned int*)(gp),           \
        (__attribute__((address_space(3))) unsigned int*)(lp), 16, 0, 0)

// LDS tile: linear [rows][64] shorts; chunk c of row r at slot c^(r&7).
__device__ __forceinline__ int lds_idx(int row, int chunk) {
    return row * 64 + ((chunk ^ (row & 7)) * 8);
}

// ---------------------------------------------------------------------------
// prep: blocks 0..767 transpose+convert weights fp32[K][N] -> bf16[N][K];
// blocks 768..791 segment bounds; blocks 792..1559 convert x -> bf16.
// ---------------------------------------------------------------------------
__global__ __launch_bounds__(256) void prep_kernel(
    const float* __restrict__ qkv_w, const float* __restrict__ out_w,
    const float* __restrict__ ff_w1, const float* __restrict__ ff_w2,
    short* __restrict__ qkvT, short* __restrict__ outT,
    short* __restrict__ ff1T, short* __restrict__ ff2T,
    const int* __restrict__ dom, int* __restrict__ seg_s,
    int* __restrict__ seg_e, const float* __restrict__ x,
    short* __restrict__ xB) {
    int b = blockIdx.x;
    if (b >= 792) {   // x -> bf16
        int i = (b - 792) * 2048 + threadIdx.x * 8;
        float4 a0 = *(const float4*)&x[i];
        float4 a1 = *(const float4*)&x[i + 4];
        short8 v = { f2bf(a0.x), f2bf(a0.y), f2bf(a0.z), f2bf(a0.w),
                     f2bf(a1.x), f2bf(a1.y), f2bf(a1.z), f2bf(a1.w) };
        *(short8*)&xB[i] = v;
        return;
    }
    if (b >= 768) {   // segment bounds
        int i = (b - 768) * 256 + threadIdx.x;
        if (i >= NP) return;
        int d = dom[i];
        int s = i;
        while (s > 0 && dom[s - 1] == d) --s;
        int e = i + 1;
        while (e < NP && dom[e] == d) ++e;
        seg_s[i] = s;
        seg_e[i] = e;
        return;
    }
    const float* src;
    short* dst;
    int K, Nn;
    if (b < 192)      { src = qkv_w; dst = qkvT; K = 256;  Nn = 768; }
    else if (b < 256) { b -= 192; src = out_w; dst = outT; K = 256;  Nn = 256; }
    else if (b < 512) { b -= 256; src = ff_w1; dst = ff1T; K = 256;  Nn = 1024; }
    else              { b -= 512; src = ff_w2; dst = ff2T; K = 1024; Nn = 256; }
    int tpr = Nn / 32;
    int k0 = (b / tpr) * 32, n0 = (b % tpr) * 32;

    __shared__ float lds[32][36];
    int t = threadIdx.x;
    {
        int k = t >> 3, n = (t & 7) * 4;
        *(float4*)&lds[k][n] = *(const float4*)&src[(size_t)(k0 + k) * Nn + n0 + n];
    }
    __syncthreads();
    {
        int n = t >> 3, ks = (t & 7) * 4;
        short4v o = { f2bf(lds[ks + 0][n]), f2bf(lds[ks + 1][n]),
                      f2bf(lds[ks + 2][n]), f2bf(lds[ks + 3][n]) };
        *(short4v*)&dst[(size_t)(n0 + n) * K + k0 + ks] = o;
    }
}

// ---------------------------------------------------------------------------
// mgemm128: C_bf16[M,Nn] = A_bf16[M,K] @ Bt_bf16[Nn,K]^T + bias (opt GELU).
// Tile 128x128, BK=64, 4 waves (2x2), wave owns 64x64 = 4x4 frags.
// ---------------------------------------------------------------------------
template <bool GELU>
__global__ __launch_bounds__(256) void mgemm128(
    const short* __restrict__ A, const short* __restrict__ Bt,
    const float* __restrict__ bias, short* __restrict__ C, int Nn, int K) {
    __shared__ __align__(16) short As[128 * 64];
    __shared__ __align__(16) short Bs[128 * 64];

    const int tid = threadIdx.x, lane = tid & 63, w = tid >> 6;
    const int wm = (w >> 1) * 64, wn = (w & 1) * 64;
    const int rowBase = blockIdx.y * 128, colBase = blockIdx.x * 128;
    const int lr = lane >> 3, sc = (lane & 7) ^ lr;
    const int fr = lane & 15, g4 = lane >> 4;

    f32x4 acc[4][4];
#pragma unroll
    for (int i = 0; i < 4; ++i)
#pragma unroll
        for (int j = 0; j < 4; ++j) acc[i][j] = f32x4{0.f, 0.f, 0.f, 0.f};

    for (int k0 = 0; k0 < K; k0 += 64) {
#pragma unroll
        for (int i = 0; i < 4; ++i) {
            int g = w * 4 + i;
            int row = g * 8 + lr;
            GLOAD16(A  + (size_t)(rowBase + row) * K + k0 + sc * 8, &As[g * 512]);
            GLOAD16(Bt + (size_t)(colBase + row) * K + k0 + sc * 8, &Bs[g * 512]);
        }
        __syncthreads();

#pragma unroll
        for (int kk = 0; kk < 2; ++kk) {
            int j = kk * 4 + g4;
            short8 af[4], bfv[4];
#pragma unroll
            for (int f = 0; f < 4; ++f) {
                af[f]  = *(const short8*)&As[lds_idx(wm + f * 16 + fr, j)];
                bfv[f] = *(const short8*)&Bs[lds_idx(wn + f * 16 + fr, j)];
            }
#pragma unroll
            for (int fm = 0; fm < 4; ++fm)
#pragma unroll
                for (int fn = 0; fn < 4; ++fn)
                    acc[fm][fn] = __builtin_amdgcn_mfma_f32_16x16x32_bf16(
                        af[fm], bfv[fn], acc[fm][fn], 0, 0, 0);
        }
        __syncthreads();
    }

    const int cr = g4 * 4;
#pragma unroll
    for (int fm = 0; fm < 4; ++fm)
#pragma unroll
        for (int fn = 0; fn < 4; ++fn) {
            int c = colBase + wn + fn * 16 + fr;
            float bv = bias[c];
#pragma unroll
            for (int j = 0; j < 4; ++j) {
                int r = rowBase + wm + fm * 16 + cr + j;
                float v = acc[fm][fn][j] + bv;
                if (GELU) v = 0.5f * v * (1.0f + erff(v * 0.70710678118654752f));
                C[(size_t)r * Nn + c] = f2bf(v);
            }
        }
}

// ---------------------------------------------------------------------------
// mgemm_res: Y_f32[M,256] = A_bf16[M,1024] @ Bt_bf16[256,1024]^T + bias +
// res_bf16. Output-tiled 128x64 (both operands tiled -> ~0.5 MB/block, the
// proven-fast geometry; replaces gemmln's block-wide-B staging which was
// ~25-30 us). Grid dim3(4, 48) = 192 blocks, 4 waves, wave owns 32x64.
// ---------------------------------------------------------------------------
__global__ __launch_bounds__(256) void mgemm_res(
    const short* __restrict__ A, const short* __restrict__ Bt,
    const float* __restrict__ bias, const short* __restrict__ res,
    float* __restrict__ Y) {
    __shared__ __align__(16) short As[128 * 64];   // 16 KB
    __shared__ __align__(16) short Bs[64 * 64];    // 8 KB

    const int tid = threadIdx.x, lane = tid & 63, w = tid >> 6;
    const int rowBase = blockIdx.y * 128, colBase = blockIdx.x * 64;
    const int lr = lane >> 3, sc = (lane & 7) ^ lr;
    const int fr = lane & 15, g4 = lane >> 4;
    const int wm = w * 32;

    f32x4 acc[2][4];
#pragma unroll
    for (int i = 0; i < 2; ++i)
#pragma unroll
        for (int j = 0; j < 4; ++j) acc[i][j] = f32x4{0.f, 0.f, 0.f, 0.f};

    for (int k0 = 0; k0 < 1024; k0 += 64) {
#pragma unroll
        for (int i = 0; i < 6; ++i) {              // 24 groups: A 16, B 8
            int g = w * 6 + i;
            if (g < 16)
                GLOAD16(A + (size_t)(rowBase + g * 8 + lr) * 1024 + k0 + sc * 8,
                        &As[g * 512]);
            else
                GLOAD16(Bt + (size_t)(colBase + (g - 16) * 8 + lr) * 1024 + k0 + sc * 8,
                        &Bs[(g - 16) * 512]);
        }
        __syncthreads();

#pragma unroll
        for (int kk = 0; kk < 2; ++kk) {
            int j = kk * 4 + g4;
            short8 af[2], bfv[4];
            af[0] = *(const short8*)&As[lds_idx(wm + fr, j)];
            af[1] = *(const short8*)&As[lds_idx(wm + 16 + fr, j)];
#pragma unroll
            for (int f = 0; f < 4; ++f)
                bfv[f] = *(const short8*)&Bs[lds_idx(f * 16 + fr, j)];
#pragma unroll
            for (int fm = 0; fm < 2; ++fm)
#pragma unroll
                for (int fn = 0; fn < 4; ++fn)
                    acc[fm][fn] = __builtin_amdgcn_mfma_f32_16x16x32_bf16(
                        af[fm], bfv[fn], acc[fm][fn], 0, 0, 0);
        }
        __syncthreads();
    }

    const int cr = g4 * 4;
#pragma unroll
    for (int fm = 0; fm < 2; ++fm)
#pragma unroll
        for (int fn = 0; fn < 4; ++fn) {
            int c = colBase + fn * 16 + fr;
            float bv = bias[c];
#pragma unroll
            for (int j = 0; j < 4; ++j) {
                int r = rowBase + wm + fm * 16 + cr + j;
                Y[(size_t)r * 256 + c] =
                    acc[fm][fn][j] + bv + bf2f(res[(size_t)r * 256 + c]);
            }
        }
}

// ---------------------------------------------------------------------------
// ln_kernel: row LayerNorm over 256 cols, one wave per row (proven in R2).
// ---------------------------------------------------------------------------
__global__ __launch_bounds__(256) void ln_kernel(
    const float* __restrict__ in, const float* __restrict__ g,
    const float* __restrict__ b, float* __restrict__ out) {
    int wid = blockIdx.x * 4 + (threadIdx.x >> 6);
    int lane = threadIdx.x & 63;

    float4 v = ((const float4*)(in + (size_t)wid * 256))[lane];
    float s = v.x + v.y + v.z + v.w;
#pragma unroll
    for (int off = 32; off; off >>= 1) s += __shfl_xor(s, off);
    float mu = s * (1.0f / 256.0f);
    float dx = v.x - mu, dy = v.y - mu, dz = v.z - mu, dw = v.w - mu;
    float ss = dx * dx + dy * dy + dz * dz + dw * dw;
#pragma unroll
    for (int off = 32; off; off >>= 1) ss += __shfl_xor(ss, off);
    float rstd = rsqrtf(ss * (1.0f / 256.0f) + LNEPS);

    float4 gg = ((const float4*)g)[lane];
    float4 bb = ((const float4*)b)[lane];
    float4 o;
    o.x = dx * rstd * gg.x + bb.x;
    o.y = dy * rstd * gg.y + bb.y;
    o.z = dz * rstd * gg.z + bb.z;
    o.w = dw * rstd * gg.w + bb.w;
    ((float4*)(out + (size_t)wid * 256))[lane] = o;
}

// ---------------------------------------------------------------------------
// attnln: fused {segment attention for 32 rows} + {out-proj GEMM} +
// {residual + LN1} -> x1 bf16. 192 blocks x 512 threads. (R6 structure.)
// ---------------------------------------------------------------------------
__global__ __launch_bounds__(512) void attnln_kernel(
    const short* __restrict__ qkvB, const int* __restrict__ seg_s,
    const int* __restrict__ seg_e, const short* __restrict__ outT,
    const float* __restrict__ out_b, const float* __restrict__ xres,
    const float* __restrict__ gw, const float* __restrict__ bw,
    short* __restrict__ x1) {
    __shared__ __align__(16) short As[32 * 256];   // attn out, swizzled
    __shared__ __align__(16) short Bs[256 * 64];
    __shared__ float r1[8][32], r2[8][32];

    const int tid = threadIdx.x, lane = tid & 63, w = tid >> 6;
    const int rowBase = blockIdx.x * 32;
    const int lr = lane >> 3, sc = (lane & 7) ^ lr;
    const int fr = lane & 15, g4 = lane >> 4;

    // ---- attention (32 rows x 4 heads = 128 tasks, 8-lane groups) ----
    {
        const int l8 = lane & 7;
        const int G  = (w << 3) | (lane >> 3);
#pragma unroll
        for (int s = 0; s < 2; ++s) {
            int task = G + s * 64;
            int r = task >> 2, h = task & 3;
            int row = rowBase + r;
            short8 qv = *(const short8*)&qkvB[(size_t)row * 768 + h * 64 + l8 * 8];
            float qd[8];
#pragma unroll
            for (int e = 0; e < 8; ++e) qd[e] = bf2f(qv[e]);
            int ss = seg_s[row], ee = seg_e[row];
            float m = -INFINITY, l = 0.0f;
            float acc[8] = {0.f, 0.f, 0.f, 0.f, 0.f, 0.f, 0.f, 0.f};
            for (int j = ss; j < ee; ++j) {
                short8 kv = *(const short8*)&qkvB[(size_t)j * 768 + 256 + h * 64 + l8 * 8];
                short8 vv = *(const short8*)&qkvB[(size_t)j * 768 + 512 + h * 64 + l8 * 8];
                float prod = 0.f;
#pragma unroll
                for (int e = 0; e < 8; ++e) prod += qd[e] * bf2f(kv[e]);
                prod += __shfl_xor(prod, 1);
                prod += __shfl_xor(prod, 2);
                prod += __shfl_xor(prod, 4);
                float score = prod * 0.125f;
                float mn = fmaxf(m, score);
                float scale = __expf(m - mn);
                float p = __expf(score - mn);
                l = l * scale + p;
#pragma unroll
                for (int e = 0; e < 8; ++e) acc[e] = acc[e] * scale + p * bf2f(vv[e]);
                m = mn;
            }
            float inv = 1.0f / l;
            int c = h * 8 + l8;
            short8 o;
#pragma unroll
            for (int e = 0; e < 8; ++e) o[e] = f2bf(acc[e] * inv);
            *(short8*)&As[r * 256 + ((c ^ (r & 7)) * 8)] = o;
        }
    }
    __syncthreads();

    // ---- GEMM (A=attn LDS, B=outT staged) + residual + LN1 ----
    f32x4 acc[2][2];
#pragma unroll
    for (int i = 0; i < 2; ++i)
#pragma unroll
        for (int j = 0; j < 2; ++j) acc[i][j] = f32x4{0.f, 0.f, 0.f, 0.f};

    for (int k0 = 0; k0 < 256; k0 += 64) {
#pragma unroll
        for (int i = 0; i < 4; ++i) {
            int g = w * 4 + i;
            GLOAD16(outT + (size_t)(g * 8 + lr) * 256 + k0 + sc * 8, &Bs[g * 512]);
        }
        __syncthreads();
#pragma unroll
        for (int kk = 0; kk < 2; ++kk) {
            int j = kk * 4 + g4;
            int cj = (k0 >> 3) + j;
            short8 af[2], bfv[2];
            af[0] = *(const short8*)&As[fr * 256 + ((cj ^ (fr & 7)) * 8)];
            af[1] = *(const short8*)&As[(16 + fr) * 256 + ((cj ^ (fr & 7)) * 8)];
#pragma unroll
            for (int fn = 0; fn < 2; ++fn)
                bfv[fn] = *(const short8*)&Bs[lds_idx(w * 32 + fn * 16 + fr, j)];
#pragma unroll
            for (int fm = 0; fm < 2; ++fm)
#pragma unroll
                for (int fn = 0; fn < 2; ++fn)
                    acc[fm][fn] = __builtin_amdgcn_mfma_f32_16x16x32_bf16(
                        af[fm], bfv[fn], acc[fm][fn], 0, 0, 0);
        }
        __syncthreads();
    }

    float v[2][2][4], p1[2][4], p2[2][4];
#pragma unroll
    for (int fm = 0; fm < 2; ++fm)
#pragma unroll
        for (int j = 0; j < 4; ++j) { p1[fm][j] = 0.f; p2[fm][j] = 0.f; }
#pragma unroll
    for (int fm = 0; fm < 2; ++fm)
#pragma unroll
        for (int fn = 0; fn < 2; ++fn) {
            int c = w * 32 + fn * 16 + fr;
            float bv = out_b[c];
#pragma unroll
            for (int j = 0; j < 4; ++j) {
                int r = rowBase + fm * 16 + g4 * 4 + j;
                float t = acc[fm][fn][j] + bv + xres[(size_t)r * 256 + c];
                v[fm][fn][j] = t;
                p1[fm][j] += t;
                p2[fm][j] += t * t;
            }
        }
#pragma unroll
    for (int m = 1; m < 16; m <<= 1)
#pragma unroll
        for (int fm = 0; fm < 2; ++fm)
#pragma unroll
            for (int j = 0; j < 4; ++j) {
                p1[fm][j] += __shfl_xor(p1[fm][j], m);
                p2[fm][j] += __shfl_xor(p2[fm][j], m);
            }
    if (fr == 0) {
#pragma unroll
        for (int fm = 0; fm < 2; ++fm)
#pragma unroll
            for (int j = 0; j < 4; ++j) {
                r1[w][fm * 16 + g4 * 4 + j] = p1[fm][j];
                r2[w][fm * 16 + g4 * 4 + j] = p2[fm][j];
            }
    }
    __syncthreads();
#pragma unroll
    for (int fm = 0; fm < 2; ++fm)
#pragma unroll
        for (int j = 0; j < 4; ++j) {
            int rl = fm * 16 + g4 * 4 + j;
            int r = rowBase + rl;
            float s1 = 0.f, s2 = 0.f;
#pragma unroll
            for (int ww = 0; ww < 8; ++ww) { s1 += r1[ww][rl]; s2 += r2[ww][rl]; }
            float mu = s1 * (1.0f / 256.0f);
            float var = s2 * (1.0f / 256.0f) - mu * mu;
            float rstd = rsqrtf(var + LNEPS);
#pragma unroll
            for (int fn = 0; fn < 2; ++fn) {
                int c = w * 32 + fn * 16 + fr;
                float o = (v[fm][fn][j] - mu) * rstd * gw[c] + bw[c];
                x1[(size_t)r * 256 + c] = f2bf(o);
            }
        }
}

// ---------------------------------------------------------------------------
extern "C" void kernel_launch(void* const* d_in, const int* in_sizes, int n_in,
                              void* d_out, int out_size, void* d_ws, size_t ws_size,
                              hipStream_t stream) {
    const float* x      = (const float*)d_in[0];
    const int*   dom    = (const int*)d_in[1];
    const float* qkv_w  = (const float*)d_in[2];
    const float* qkv_b  = (const float*)d_in[3];
    const float* out_w  = (const float*)d_in[4];
    const float* out_b  = (const float*)d_in[5];
    const float* ff_w1  = (const float*)d_in[6];
    const float* ff_b1  = (const float*)d_in[7];
    const float* ff_w2  = (const float*)d_in[8];
    const float* ff_b2  = (const float*)d_in[9];
    const float* ln1_g  = (const float*)d_in[10];
    const float* ln1_b  = (const float*)d_in[11];
    const float* ln2_g  = (const float*)d_in[12];
    const float* ln2_b  = (const float*)d_in[13];
    float* out = (float*)d_out;

    short* xB     = (short*)d_ws;                    // NP x 256
    short* qkvB   = xB + (size_t)NP * 256;           // NP x 768
    short* x1     = qkvB + (size_t)NP * 768;         // NP x 256
    short* hB     = x1 + (size_t)NP * 256;           // NP x 1024
    short* qkvT   = hB + (size_t)NP * 1024;          // 768 x 256
    short* outT   = qkvT + 768 * 256;                // 256 x 256
    short* ff1T   = outT + 256 * 256;                // 1024 x 256
    short* ff2T   = ff1T + 1024 * 256;               // 256 x 1024
    int* seg_s    = (int*)(ff2T + 256 * 1024);
    int* seg_e    = seg_s + NP;
    float* y      = (float*)(seg_e + NP);            // NP x 256 fp32

    // 0) weight transpose/convert + segment bounds + x->bf16
    prep_kernel<<<1560, 256, 0, stream>>>(qkv_w, out_w, ff_w1, ff_w2,
                                          qkvT, outT, ff1T, ff2T,
                                          dom, seg_s, seg_e, x, xB);

    // 1) qkv = x @ qkv_w + qkv_b                (bf16 out)
    mgemm128<false><<<dim3(768 / 128, NP / 128), 256, 0, stream>>>(
        xB, qkvT, qkv_b, qkvB, 768, 256);

    // 2) x1 = LN1(x + attn(qkv) @ out_w + out_b)   (fused, bf16 out)
    attnln_kernel<<<NP / 32, 512, 0, stream>>>(
        qkvB, seg_s, seg_e, outT, out_b, x, ln1_g, ln1_b, x1);

    // 3) h = gelu(x1 @ ff_w1 + ff_b1)           (bf16 out)
    mgemm128<true><<<dim3(DFF / 128, NP / 128), 256, 0, stream>>>(
        x1, ff1T, ff_b1, hB, 1024, 256);

    // 4) y = x1 + h @ ff_w2 + ff_b2             (fp32 out, output-tiled)
    mgemm_res<<<dim3(DM / 64, NP / 128), 256, 0, stream>>>(
        hB, ff2T, ff_b2, x1, y);

    // 5) out = LN2(y)
    ln_kernel<<<NP / 4, 256, 0, stream>>>(y, ln2_g, ln2_b, out);
}

// Round 14
// 68.220 us; speedup vs baseline: 1.3156x; 1.1388x over previous
//
#include <hip/hip_runtime.h>
#include <hip/hip_bf16.h>
#include <math.h>

constexpr int NP  = 6144;   // rows
constexpr int DM  = 256;    // d_model
constexpr int DFF = 1024;   // ff dim
constexpr float LNEPS = 1e-5f;

typedef __attribute__((ext_vector_type(8))) short short8;
typedef __attribute__((ext_vector_type(4))) short short4v;
typedef __attribute__((ext_vector_type(4))) float f32x4;

__device__ __forceinline__ short f2bf(float f) {
    unsigned u = __builtin_bit_cast(unsigned, f);
    unsigned r = u + 0x7FFFu + ((u >> 16) & 1u);   // RNE
    return (short)(r >> 16);
}
__device__ __forceinline__ float bf2f(short s) {
    unsigned u = ((unsigned)(unsigned short)s) << 16;
    return __builtin_bit_cast(float, u);
}

// global->LDS direct 16B copy. LDS dest = wave-uniform base + lane*16;
// per-lane global src carries the swizzle (guide rule #21).
#define GLOAD16(gp, lp)                                                        \
    __builtin_amdgcn_global_load_lds(                                          \
        (const __attribute__((address_space(1))) unsigned int*)(gp),           \
        (__attribute__((address_space(3))) unsigned int*)(lp), 16, 0, 0)

// LDS tile: linear [rows][64] shorts; chunk c of row r at slot c^(r&7).
__device__ __forceinline__ int lds_idx(int row, int chunk) {
    return row * 64 + ((chunk ^ (row & 7)) * 8);
}

// ---------------------------------------------------------------------------
// prep: blocks 0..767 transpose+convert weights fp32[K][N] -> bf16[N][K];
// blocks 768..791 segment bounds; blocks 792..1559 convert x -> bf16.
// ---------------------------------------------------------------------------
__global__ __launch_bounds__(256) void prep_kernel(
    const float* __restrict__ qkv_w, const float* __restrict__ out_w,
    const float* __restrict__ ff_w1, const float* __restrict__ ff_w2,
    short* __restrict__ qkvT, short* __restrict__ outT,
    short* __restrict__ ff1T, short* __restrict__ ff2T,
    const int* __restrict__ dom, int* __restrict__ seg_s,
    int* __restrict__ seg_e, const float* __restrict__ x,
    short* __restrict__ xB) {
    int b = blockIdx.x;
    if (b >= 792) {   // x -> bf16
        int i = (b - 792) * 2048 + threadIdx.x * 8;
        float4 a0 = *(const float4*)&x[i];
        float4 a1 = *(const float4*)&x[i + 4];
        short8 v = { f2bf(a0.x), f2bf(a0.y), f2bf(a0.z), f2bf(a0.w),
                     f2bf(a1.x), f2bf(a1.y), f2bf(a1.z), f2bf(a1.w) };
        *(short8*)&xB[i] = v;
        return;
    }
    if (b >= 768) {   // segment bounds
        int i = (b - 768) * 256 + threadIdx.x;
        if (i >= NP) return;
        int d = dom[i];
        int s = i;
        while (s > 0 && dom[s - 1] == d) --s;
        int e = i + 1;
        while (e < NP && dom[e] == d) ++e;
        seg_s[i] = s;
        seg_e[i] = e;
        return;
    }
    const float* src;
    short* dst;
    int K, Nn;
    if (b < 192)      { src = qkv_w; dst = qkvT; K = 256;  Nn = 768; }
    else if (b < 256) { b -= 192; src = out_w; dst = outT; K = 256;  Nn = 256; }
    else if (b < 512) { b -= 256; src = ff_w1; dst = ff1T; K = 256;  Nn = 1024; }
    else              { b -= 512; src = ff_w2; dst = ff2T; K = 1024; Nn = 256; }
    int tpr = Nn / 32;
    int k0 = (b / tpr) * 32, n0 = (b % tpr) * 32;

    __shared__ float lds[32][36];
    int t = threadIdx.x;
    {
        int k = t >> 3, n = (t & 7) * 4;
        *(float4*)&lds[k][n] = *(const float4*)&src[(size_t)(k0 + k) * Nn + n0 + n];
    }
    __syncthreads();
    {
        int n = t >> 3, ks = (t & 7) * 4;
        short4v o = { f2bf(lds[ks + 0][n]), f2bf(lds[ks + 1][n]),
                      f2bf(lds[ks + 2][n]), f2bf(lds[ks + 3][n]) };
        *(short4v*)&dst[(size_t)(n0 + n) * K + k0 + ks] = o;
    }
}

// ---------------------------------------------------------------------------
// mgemm64: 64x64 tiles for grid >> 256 CUs. At 1 block/CU (R13's 128-tiles,
// 192-384 blocks) every k-step's vmcnt(0) barrier drain (~900cy) is fully
// exposed; 64x64 gives 384-1536 blocks -> 2-6 blocks/CU so other blocks'
// MFMA hides the drain (m114 overlap). 4 waves (2x2), wave owns 32x32.
// EPI: 0 -> bf16 C; 1 -> gelu, bf16 C; 2 -> +res(bf16), fp32 C (Nn==256).
// ---------------------------------------------------------------------------
template <int EPI>
__global__ __launch_bounds__(256) void mgemm64(
    const short* __restrict__ A, const short* __restrict__ Bt,
    const float* __restrict__ bias, const short* __restrict__ res,
    void* __restrict__ Cv, int Nn, int K) {
    __shared__ __align__(16) short As[64 * 64];   // 8 KB
    __shared__ __align__(16) short Bs[64 * 64];   // 8 KB

    const int tid = threadIdx.x, lane = tid & 63, w = tid >> 6;
    const int wm = (w >> 1) * 32, wn = (w & 1) * 32;
    const int rowBase = blockIdx.y * 64, colBase = blockIdx.x * 64;
    const int lr = lane >> 3, sc = (lane & 7) ^ lr;
    const int fr = lane & 15, g4 = lane >> 4;

    f32x4 acc[2][2];
#pragma unroll
    for (int i = 0; i < 2; ++i)
#pragma unroll
        for (int j = 0; j < 2; ++j) acc[i][j] = f32x4{0.f, 0.f, 0.f, 0.f};

    for (int k0 = 0; k0 < K; k0 += 64) {
#pragma unroll
        for (int i = 0; i < 2; ++i) {
            int g = w * 2 + i;
            int row = g * 8 + lr;
            GLOAD16(A  + (size_t)(rowBase + row) * K + k0 + sc * 8, &As[g * 512]);
            GLOAD16(Bt + (size_t)(colBase + row) * K + k0 + sc * 8, &Bs[g * 512]);
        }
        __syncthreads();

#pragma unroll
        for (int kk = 0; kk < 2; ++kk) {
            int j = kk * 4 + g4;
            short8 af[2], bfv[2];
#pragma unroll
            for (int f = 0; f < 2; ++f) {
                af[f]  = *(const short8*)&As[lds_idx(wm + f * 16 + fr, j)];
                bfv[f] = *(const short8*)&Bs[lds_idx(wn + f * 16 + fr, j)];
            }
#pragma unroll
            for (int fm = 0; fm < 2; ++fm)
#pragma unroll
                for (int fn = 0; fn < 2; ++fn)
                    acc[fm][fn] = __builtin_amdgcn_mfma_f32_16x16x32_bf16(
                        af[fm], bfv[fn], acc[fm][fn], 0, 0, 0);
        }
        __syncthreads();
    }

    const int cr = g4 * 4;
#pragma unroll
    for (int fm = 0; fm < 2; ++fm)
#pragma unroll
        for (int fn = 0; fn < 2; ++fn) {
            int c = colBase + wn + fn * 16 + fr;
            float bv = bias[c];
#pragma unroll
            for (int j = 0; j < 4; ++j) {
                int r = rowBase + wm + fm * 16 + cr + j;
                float v = acc[fm][fn][j] + bv;
                if (EPI == 1) v = 0.5f * v * (1.0f + erff(v * 0.70710678118654752f));
                if (EPI == 2)
                    ((float*)Cv)[(size_t)r * Nn + c] =
                        v + bf2f(res[(size_t)r * 256 + c]);
                else
                    ((short*)Cv)[(size_t)r * Nn + c] = f2bf(v);
            }
        }
}

// ---------------------------------------------------------------------------
// ln_kernel: row LayerNorm over 256 cols, one wave per row (proven in R2).
// ---------------------------------------------------------------------------
__global__ __launch_bounds__(256) void ln_kernel(
    const float* __restrict__ in, const float* __restrict__ g,
    const float* __restrict__ b, float* __restrict__ out) {
    int wid = blockIdx.x * 4 + (threadIdx.x >> 6);
    int lane = threadIdx.x & 63;

    float4 v = ((const float4*)(in + (size_t)wid * 256))[lane];
    float s = v.x + v.y + v.z + v.w;
#pragma unroll
    for (int off = 32; off; off >>= 1) s += __shfl_xor(s, off);
    float mu = s * (1.0f / 256.0f);
    float dx = v.x - mu, dy = v.y - mu, dz = v.z - mu, dw = v.w - mu;
    float ss = dx * dx + dy * dy + dz * dz + dw * dw;
#pragma unroll
    for (int off = 32; off; off >>= 1) ss += __shfl_xor(ss, off);
    float rstd = rsqrtf(ss * (1.0f / 256.0f) + LNEPS);

    float4 gg = ((const float4*)g)[lane];
    float4 bb = ((const float4*)b)[lane];
    float4 o;
    o.x = dx * rstd * gg.x + bb.x;
    o.y = dy * rstd * gg.y + bb.y;
    o.z = dz * rstd * gg.z + bb.z;
    o.w = dw * rstd * gg.w + bb.w;
    ((float4*)(out + (size_t)wid * 256))[lane] = o;
}

// ---------------------------------------------------------------------------
// attnln: fused {segment attention for 32 rows} + {out-proj GEMM} +
// {residual + LN1} -> x1 bf16. 192 blocks x 512 threads. (R6 structure.)
// ---------------------------------------------------------------------------
__global__ __launch_bounds__(512) void attnln_kernel(
    const short* __restrict__ qkvB, const int* __restrict__ seg_s,
    const int* __restrict__ seg_e, const short* __restrict__ outT,
    const float* __restrict__ out_b, const float* __restrict__ xres,
    const float* __restrict__ gw, const float* __restrict__ bw,
    short* __restrict__ x1) {
    __shared__ __align__(16) short As[32 * 256];   // attn out, swizzled
    __shared__ __align__(16) short Bs[256 * 64];
    __shared__ float r1[8][32], r2[8][32];

    const int tid = threadIdx.x, lane = tid & 63, w = tid >> 6;
    const int rowBase = blockIdx.x * 32;
    const int lr = lane >> 3, sc = (lane & 7) ^ lr;
    const int fr = lane & 15, g4 = lane >> 4;

    // ---- attention (32 rows x 4 heads = 128 tasks, 8-lane groups) ----
    {
        const int l8 = lane & 7;
        const int G  = (w << 3) | (lane >> 3);
#pragma unroll
        for (int s = 0; s < 2; ++s) {
            int task = G + s * 64;
            int r = task >> 2, h = task & 3;
            int row = rowBase + r;
            short8 qv = *(const short8*)&qkvB[(size_t)row * 768 + h * 64 + l8 * 8];
            float qd[8];
#pragma unroll
            for (int e = 0; e < 8; ++e) qd[e] = bf2f(qv[e]);
            int ss = seg_s[row], ee = seg_e[row];
            float m = -INFINITY, l = 0.0f;
            float acc[8] = {0.f, 0.f, 0.f, 0.f, 0.f, 0.f, 0.f, 0.f};
            for (int j = ss; j < ee; ++j) {
                short8 kv = *(const short8*)&qkvB[(size_t)j * 768 + 256 + h * 64 + l8 * 8];
                short8 vv = *(const short8*)&qkvB[(size_t)j * 768 + 512 + h * 64 + l8 * 8];
                float prod = 0.f;
#pragma unroll
                for (int e = 0; e < 8; ++e) prod += qd[e] * bf2f(kv[e]);
                prod += __shfl_xor(prod, 1);
                prod += __shfl_xor(prod, 2);
                prod += __shfl_xor(prod, 4);
                float score = prod * 0.125f;
                float mn = fmaxf(m, score);
                float scale = __expf(m - mn);
                float p = __expf(score - mn);
                l = l * scale + p;
#pragma unroll
                for (int e = 0; e < 8; ++e) acc[e] = acc[e] * scale + p * bf2f(vv[e]);
                m = mn;
            }
            float inv = 1.0f / l;
            int c = h * 8 + l8;
            short8 o;
#pragma unroll
            for (int e = 0; e < 8; ++e) o[e] = f2bf(acc[e] * inv);
            *(short8*)&As[r * 256 + ((c ^ (r & 7)) * 8)] = o;
        }
    }
    __syncthreads();

    // ---- GEMM (A=attn LDS, B=outT staged) + residual + LN1 ----
    f32x4 acc[2][2];
#pragma unroll
    for (int i = 0; i < 2; ++i)
#pragma unroll
        for (int j = 0; j < 2; ++j) acc[i][j] = f32x4{0.f, 0.f, 0.f, 0.f};

    for (int k0 = 0; k0 < 256; k0 += 64) {
#pragma unroll
        for (int i = 0; i < 4; ++i) {
            int g = w * 4 + i;
            GLOAD16(outT + (size_t)(g * 8 + lr) * 256 + k0 + sc * 8, &Bs[g * 512]);
        }
        __syncthreads();
#pragma unroll
        for (int kk = 0; kk < 2; ++kk) {
            int j = kk * 4 + g4;
            int cj = (k0 >> 3) + j;
            short8 af[2], bfv[2];
            af[0] = *(const short8*)&As[fr * 256 + ((cj ^ (fr & 7)) * 8)];
            af[1] = *(const short8*)&As[(16 + fr) * 256 + ((cj ^ (fr & 7)) * 8)];
#pragma unroll
            for (int fn = 0; fn < 2; ++fn)
                bfv[fn] = *(const short8*)&Bs[lds_idx(w * 32 + fn * 16 + fr, j)];
#pragma unroll
            for (int fm = 0; fm < 2; ++fm)
#pragma unroll
                for (int fn = 0; fn < 2; ++fn)
                    acc[fm][fn] = __builtin_amdgcn_mfma_f32_16x16x32_bf16(
                        af[fm], bfv[fn], acc[fm][fn], 0, 0, 0);
        }
        __syncthreads();
    }

    float v[2][2][4], p1[2][4], p2[2][4];
#pragma unroll
    for (int fm = 0; fm < 2; ++fm)
#pragma unroll
        for (int j = 0; j < 4; ++j) { p1[fm][j] = 0.f; p2[fm][j] = 0.f; }
#pragma unroll
    for (int fm = 0; fm < 2; ++fm)
#pragma unroll
        for (int fn = 0; fn < 2; ++fn) {
            int c = w * 32 + fn * 16 + fr;
            float bv = out_b[c];
#pragma unroll
            for (int j = 0; j < 4; ++j) {
                int r = rowBase + fm * 16 + g4 * 4 + j;
                float t = acc[fm][fn][j] + bv + xres[(size_t)r * 256 + c];
                v[fm][fn][j] = t;
                p1[fm][j] += t;
                p2[fm][j] += t * t;
            }
        }
#pragma unroll
    for (int m = 1; m < 16; m <<= 1)
#pragma unroll
        for (int fm = 0; fm < 2; ++fm)
#pragma unroll
            for (int j = 0; j < 4; ++j) {
                p1[fm][j] += __shfl_xor(p1[fm][j], m);
                p2[fm][j] += __shfl_xor(p2[fm][j], m);
            }
    if (fr == 0) {
#pragma unroll
        for (int fm = 0; fm < 2; ++fm)
#pragma unroll
            for (int j = 0; j < 4; ++j) {
                r1[w][fm * 16 + g4 * 4 + j] = p1[fm][j];
                r2[w][fm * 16 + g4 * 4 + j] = p2[fm][j];
            }
    }
    __syncthreads();
#pragma unroll
    for (int fm = 0; fm < 2; ++fm)
#pragma unroll
        for (int j = 0; j < 4; ++j) {
            int rl = fm * 16 + g4 * 4 + j;
            int r = rowBase + rl;
            float s1 = 0.f, s2 = 0.f;
#pragma unroll
            for (int ww = 0; ww < 8; ++ww) { s1 += r1[ww][rl]; s2 += r2[ww][rl]; }
            float mu = s1 * (1.0f / 256.0f);
            float var = s2 * (1.0f / 256.0f) - mu * mu;
            float rstd = rsqrtf(var + LNEPS);
#pragma unroll
            for (int fn = 0; fn < 2; ++fn) {
                int c = w * 32 + fn * 16 + fr;
                float o = (v[fm][fn][j] - mu) * rstd * gw[c] + bw[c];
                x1[(size_t)r * 256 + c] = f2bf(o);
            }
        }
}

// ---------------------------------------------------------------------------
extern "C" void kernel_launch(void* const* d_in, const int* in_sizes, int n_in,
                              void* d_out, int out_size, void* d_ws, size_t ws_size,
                              hipStream_t stream) {
    const float* x      = (const float*)d_in[0];
    const int*   dom    = (const int*)d_in[1];
    const float* qkv_w  = (const float*)d_in[2];
    const float* qkv_b  = (const float*)d_in[3];
    const float* out_w  = (const float*)d_in[4];
    const float* out_b  = (const float*)d_in[5];
    const float* ff_w1  = (const float*)d_in[6];
    const float* ff_b1  = (const float*)d_in[7];
    const float* ff_w2  = (const float*)d_in[8];
    const float* ff_b2  = (const float*)d_in[9];
    const float* ln1_g  = (const float*)d_in[10];
    const float* ln1_b  = (const float*)d_in[11];
    const float* ln2_g  = (const float*)d_in[12];
    const float* ln2_b  = (const float*)d_in[13];
    float* out = (float*)d_out;

    short* xB     = (short*)d_ws;                    // NP x 256
    short* qkvB   = xB + (size_t)NP * 256;           // NP x 768
    short* x1     = qkvB + (size_t)NP * 768;         // NP x 256
    short* hB     = x1 + (size_t)NP * 256;           // NP x 1024
    short* qkvT   = hB + (size_t)NP * 1024;          // 768 x 256
    short* outT   = qkvT + 768 * 256;                // 256 x 256
    short* ff1T   = outT + 256 * 256;                // 1024 x 256
    short* ff2T   = ff1T + 1024 * 256;               // 256 x 1024
    int* seg_s    = (int*)(ff2T + 256 * 1024);
    int* seg_e    = seg_s + NP;
    float* y      = (float*)(seg_e + NP);            // NP x 256 fp32

    // 0) weight transpose/convert + segment bounds + x->bf16
    prep_kernel<<<1560, 256, 0, stream>>>(qkv_w, out_w, ff_w1, ff_w2,
                                          qkvT, outT, ff1T, ff2T,
                                          dom, seg_s, seg_e, x, xB);

    // 1) qkv = x @ qkv_w + qkv_b                (bf16 out, 1152 blocks)
    mgemm64<0><<<dim3(768 / 64, NP / 64), 256, 0, stream>>>(
        xB, qkvT, qkv_b, nullptr, qkvB, 768, 256);

    // 2) x1 = LN1(x + attn(qkv) @ out_w + out_b)   (fused, bf16 out)
    attnln_kernel<<<NP / 32, 512, 0, stream>>>(
        qkvB, seg_s, seg_e, outT, out_b, x, ln1_g, ln1_b, x1);

    // 3) h = gelu(x1 @ ff_w1 + ff_b1)           (bf16 out, 1536 blocks)
    mgemm64<1><<<dim3(DFF / 64, NP / 64), 256, 0, stream>>>(
        x1, ff1T, ff_b1, nullptr, hB, 1024, 256);

    // 4) y = x1 + h @ ff_w2 + ff_b2             (fp32 out, 384 blocks)
    mgemm64<2><<<dim3(DM / 64, NP / 64), 256, 0, stream>>>(
        hB, ff2T, ff_b2, x1, y, 256, 1024);

    // 5) out = LN2(y)
    ln_kernel<<<NP / 4, 256, 0, stream>>>(y, ln2_g, ln2_b, out);
}